// Round 7
// baseline (909.085 us; speedup 1.0000x reference)
//
#include <hip/hip_runtime.h>
#include <hip/hip_fp16.h>

typedef unsigned int uint;

#define GB_D 64           // destinations per bucket
#define MS_CH 16384       // edges per multisplit block (longer bucket runs -> less write amplification)
#define BS_CAP 6912       // max edges staged per bucket in k_bsort LDS

using h8  = __attribute__((ext_vector_type(8))) _Float16;
using h4  = __attribute__((ext_vector_type(4))) _Float16;
using f4v = __attribute__((ext_vector_type(4))) float;

__device__ __forceinline__ float4 ld4(const float* p) { return *reinterpret_cast<const float4*>(p); }
__device__ __forceinline__ void st4(float* p, float4 v) { *reinterpret_cast<float4*>(p) = v; }
__device__ __forceinline__ void fma4(float4& a, float s, const float4 w) {
    a.x = fmaf(s, w.x, a.x); a.y = fmaf(s, w.y, a.y);
    a.z = fmaf(s, w.z, a.z); a.w = fmaf(s, w.w, a.w);
}
__device__ __forceinline__ uint pk2(float a, float b) {
    __half2 h = __floats2half2_rn(a, b);
    return *reinterpret_cast<uint*>(&h);
}

// ---------------- bucket histogram (both directions fused) ----------------
__global__ __launch_bounds__(256) void k_bhist(const int* __restrict__ row, const int* __restrict__ col,
                                               int nnz, int* __restrict__ bcnt, int nbc, int nbt) {
    extern __shared__ int ls[];
    for (int b = threadIdx.x; b < nbt; b += blockDim.x) ls[b] = 0;
    __syncthreads();
    int i0 = blockIdx.x * blockDim.x + threadIdx.x;
    int stride = gridDim.x * blockDim.x;
    for (int i = i0; i < nnz; i += stride) {
        atomicAdd(&ls[col[i] >> 6], 1);
        atomicAdd(&ls[nbc + (row[i] >> 6)], 1);
    }
    __syncthreads();
    for (int b = threadIdx.x; b < nbt; b += blockDim.x) {
        int c = ls[b];
        if (c) atomicAdd(&bcnt[b], c);
    }
}

// ---------------- single-block exclusive scan over nbt buckets ----------------
__global__ __launch_bounds__(1024) void k_bscan(const int* __restrict__ cnt, int n,
                                                int* __restrict__ ptr, int* __restrict__ nxt) {
    __shared__ int wsum[17];
    __shared__ int carry, tot;
    if (threadIdx.x == 0) carry = 0;
    __syncthreads();
    int lane = threadIdx.x & 63;
    int wid  = threadIdx.x >> 6;
    for (int base = 0; base < n; base += 1024) {
        int idx = base + (int)threadIdx.x;
        int v = (idx < n) ? cnt[idx] : 0;
        int inc = v;
        #pragma unroll
        for (int off = 1; off < 64; off <<= 1) {
            int t = __shfl_up(inc, (unsigned)off, 64);
            if (lane >= off) inc += t;
        }
        if (lane == 63) wsum[wid] = inc;
        __syncthreads();
        if (threadIdx.x == 0) {
            int s = 0;
            for (int w = 0; w < 16; w++) { int t = wsum[w]; wsum[w] = s; s += t; }
            tot = s;
        }
        __syncthreads();
        int excl = carry + wsum[wid] + (inc - v);
        if (idx < n) { ptr[idx] = excl; nxt[idx] = excl; }
        __syncthreads();
        if (threadIdx.x == 0) carry += tot;
        __syncthreads();
    }
    if (threadIdx.x == 0) ptr[n] = carry;
}

// ---------------- multisplit scatter into bucket-grouped edge array ----------------
// pack.x = (dest&63)<<20 | src ; pack.y = f32 bits of |adj|
__global__ __launch_bounds__(256) void k_mpsplit(const int* __restrict__ row, const int* __restrict__ col,
                                                 const float* __restrict__ adj, int nnz,
                                                 int* __restrict__ bnxt, int2* __restrict__ pack,
                                                 int nbc, int nbt) {
    extern __shared__ int ls[];
    const int t = threadIdx.x;
    for (int b = t; b < nbt; b += 256) ls[b] = 0;
    __syncthreads();
    const int start = blockIdx.x * MS_CH;
    const int end = min(start + MS_CH, nnz);
    for (int i = start + t; i < end; i += 256) {
        atomicAdd(&ls[col[i] >> 6], 1);
        atomicAdd(&ls[nbc + (row[i] >> 6)], 1);
    }
    __syncthreads();
    for (int b = t; b < nbt; b += 256) {
        int c = ls[b];
        ls[b] = c ? atomicAdd(&bnxt[b], c) : 0;
    }
    __syncthreads();
    for (int i = start + t; i < end; i += 256) {
        int r = row[i], c = col[i];
        int vb = __float_as_int(fabsf(adj[i]));
        int p1 = atomicAdd(&ls[c >> 6], 1);
        pack[p1] = make_int2(((c & 63) << 20) | r, vb);
        int p2 = atomicAdd(&ls[nbc + (r >> 6)], 1);
        pack[p2] = make_int2(((r & 63) << 20) | c, vb);
    }
}

// ---------------- in-bucket counting sort (in place via LDS staging) + per-dest ptr ----------------
__global__ __launch_bounds__(256) void k_bsort(const int* __restrict__ bptr, int2* __restrict__ pack,
                                               int* __restrict__ dptr_c, int C,
                                               int* __restrict__ dptr_v, int V, int nbc) {
    __shared__ int2 ebuf[BS_CAP];
    __shared__ int h[GB_D];
    __shared__ int cur[GB_D];
    const int b = blockIdx.x, t = threadIdx.x;
    const int s = bptr[b], e = bptr[b + 1];
    const int n = min(e - s, BS_CAP);
    if (t < GB_D) h[t] = 0;
    __syncthreads();
    for (int i = t; i < n; i += 256) {
        int2 ed = pack[s + i];
        ebuf[i] = ed;
        atomicAdd(&h[((uint)ed.x) >> 20], 1);
    }
    __syncthreads();
    if (t < GB_D) {
        int v = h[t];
        int inc = v;
        #pragma unroll
        for (int off = 1; off < 64; off <<= 1) {
            int u = __shfl_up(inc, (unsigned)off, 64);
            if (t >= off) inc += u;
        }
        int excl = inc - v;
        cur[t] = excl;
        const bool isC = (b < nbc);
        const int base = (isC ? b : b - nbc) << 6;
        const int nd   = isC ? C : V;
        int* dp        = isC ? dptr_c : dptr_v;
        const int d = base + t;
        if (d < nd) dp[d] = s + excl;
        if (d == nd - 1) dp[nd] = s + n;
    }
    __syncthreads();
    for (int i = t; i < n; i += 256) {
        int2 ed = ebuf[i];
        int p = atomicAdd(&cur[((uint)ed.x) >> 20], 1);
        pack[s + p] = make_int2(ed.x & 0xFFFFF, ed.y);
    }
}

// ---------------- gather: one wave per destination, fp16 source mirror, fp32 accumulate ----------------
__global__ __launch_bounds__(256) void k_gather(const int* __restrict__ dptr,
                                                const int2* __restrict__ es,
                                                const __half* __restrict__ sfeat,
                                                float* __restrict__ dmsg, int n) {
    int wid = (int)((blockIdx.x * blockDim.x + threadIdx.x) >> 6);
    int lane = threadIdx.x & 63;
    int nw = (int)((gridDim.x * blockDim.x) >> 6);
    for (int d = wid; d < n; d += nw) {
        int s = dptr[d], e = dptr[d + 1];
        float a0 = 0.f, a1 = 0.f, a2 = 0.f, a3 = 0.f;
        int i = s;
        for (; i + 3 < e; i += 4) {
            int2 e0 = es[i], e1 = es[i + 1], e2 = es[i + 2], e3 = es[i + 3];
            a0 = fmaf(__int_as_float(e0.y), __half2float(sfeat[(size_t)e0.x * 64 + lane]), a0);
            a1 = fmaf(__int_as_float(e1.y), __half2float(sfeat[(size_t)e1.x * 64 + lane]), a1);
            a2 = fmaf(__int_as_float(e2.y), __half2float(sfeat[(size_t)e2.x * 64 + lane]), a2);
            a3 = fmaf(__int_as_float(e3.y), __half2float(sfeat[(size_t)e3.x * 64 + lane]), a3);
        }
        for (; i < e; i++) {
            int2 e0 = es[i];
            a0 = fmaf(__int_as_float(e0.y), __half2float(sfeat[(size_t)e0.x * 64 + lane]), a0);
        }
        dmsg[(size_t)d * 64 + lane] = (a0 + a1) + (a2 + a3);
    }
}

// ---------------- feature init: fp32 ones + fp16 mirror ones ----------------
__global__ __launch_bounds__(256) void k_ones2(float4* p, int n4, uint4* ph, int n4h) {
    int i0 = blockIdx.x * blockDim.x + threadIdx.x;
    int stride = gridDim.x * blockDim.x;
    float4 one = make_float4(1.f, 1.f, 1.f, 1.f);
    uint4 oneh = make_uint4(0x3C003C00u, 0x3C003C00u, 0x3C003C00u, 0x3C003C00u);
    for (int i = i0; i < n4; i += stride) p[i] = one;
    for (int i = i0; i < n4h; i += stride) ph[i] = oneh;
}

// ---------------- prepare_cond: 1 -> 128 relu -> 64 (fp32 + fp16 mirror) ----------------
__global__ __launch_bounds__(256) void k_pc2(const float* __restrict__ cond, float* __restrict__ constraints,
                                             __half* __restrict__ conh, int C,
                                             const float* __restrict__ w1, const float* __restrict__ b1,
                                             const float* __restrict__ w2, const float* __restrict__ b2) {
    __shared__ float hs[64][132];
    __shared__ float cs[64];
    const int t = threadIdx.x;
    const int base = blockIdx.x * 64;
    const int rem = C - base;

    if (t < 64) cs[t] = (t < rem) ? cond[base + t] : 0.f;
    __syncthreads();

    #pragma unroll
    for (int j = 0; j < 32; j++) {
        int idx = j * 256 + t;
        int k = idx & 127, row = idx >> 7;
        hs[row][k] = fmaxf(fmaf(cs[row], w1[k], b1[k]), 0.f);
    }
    __syncthreads();

    const int tx2 = t & 15, ty2 = t >> 4;
    float4 bb = ld4(b2 + tx2 * 4);
    float4 acc[4] = { bb, bb, bb, bb };
    const float* w2p = w2 + tx2 * 4;
    #pragma unroll 4
    for (int k = 0; k < 128; k++) {
        float4 w = ld4(w2p + k * 64);
        fma4(acc[0], hs[ty2 * 4 + 0][k], w);
        fma4(acc[1], hs[ty2 * 4 + 1][k], w);
        fma4(acc[2], hs[ty2 * 4 + 2][k], w);
        fma4(acc[3], hs[ty2 * 4 + 3][k], w);
    }
    #pragma unroll
    for (int r = 0; r < 4; r++) {
        int row = ty2 * 4 + r;
        if (row < rem) {
            st4(&constraints[(size_t)(base + row) * 64 + tx2 * 4], acc[r]);
            uint2 o;
            o.x = pk2(acc[r].x, acc[r].y);
            o.y = pk2(acc[r].z, acc[r].w);
            *(uint2*)(conh + (size_t)(base + row) * 64 + tx2 * 4) = o;
        }
    }
}

// ---------------- update MLP via MFMA: concat(feat,msg)[128] -> 128 relu -> 64, in-place ----------------
// fp16 MFMA with hi/lo activation split, fp32 accumulate; writes fp32 canonical + fp16 mirror.
__global__ __launch_bounds__(256) void k_mlp3(float* __restrict__ feat, const float* __restrict__ msg,
                                              __half* __restrict__ mirror, int n,
                                              const float* __restrict__ w1, const float* __restrict__ b1,
                                              const float* __restrict__ w2, const float* __restrict__ b2) {
    __shared__ _Float16 xh[64][136];   // x (later h) hi
    __shared__ _Float16 xl[64][136];   // x (later h) lo
    const int t = threadIdx.x;
    const int base = blockIdx.x * 64;
    const int rem = n - base;
    const int wv = t >> 6;            // wave 0..3
    const int la = t & 15;            // lane&15  : A-row / B-col / D-col index
    const int lb = (t & 63) >> 4;     // lane>>4  : k-chunk / D-row group

    // ---- stage x = concat(feat,msg) as fp16 hi + lo ----
    {
        const float4* f4p = (const float4*)(feat + (size_t)base * 64);
        const float4* m4p = (const float4*)(msg + (size_t)base * 64);
        #pragma unroll
        for (int j = 0; j < 8; j++) {
            int idx = j * 256 + t;          // 0..2047
            int row = idx >> 5;             // 0..63
            int q   = idx & 31;             // 0..31  (16 feat quads + 16 msg quads)
            float4 v = make_float4(0.f, 0.f, 0.f, 0.f);
            if (row < rem) v = (q < 16) ? f4p[row * 16 + q] : m4p[row * 16 + (q - 16)];
            int k = (q < 16) ? q * 4 : 64 + (q - 16) * 4;
            h4 hi, lo;
            hi[0] = (_Float16)v.x; lo[0] = (_Float16)(v.x - (float)hi[0]);
            hi[1] = (_Float16)v.y; lo[1] = (_Float16)(v.y - (float)hi[1]);
            hi[2] = (_Float16)v.z; lo[2] = (_Float16)(v.z - (float)hi[2]);
            hi[3] = (_Float16)v.w; lo[3] = (_Float16)(v.w - (float)hi[3]);
            *(h4*)&xh[row][k] = hi;
            *(h4*)&xl[row][k] = lo;
        }
    }

    // ---- weight fragments (fp16) into registers ----
    h8 B1[2][4];   // layer1: wave's 2 col-tiles x 4 k-chunks
    h8 B2[4];      // layer2: wave's 1 col-tile x 4 k-chunks
    #pragma unroll
    for (int nn = 0; nn < 2; nn++) {
        int col = wv * 32 + nn * 16 + la;
        #pragma unroll
        for (int kc = 0; kc < 4; kc++) {
            int kb = kc * 32 + lb * 8;
            h8 bb;
            #pragma unroll
            for (int j = 0; j < 8; j++) bb[j] = (_Float16)w1[(kb + j) * 128 + col];
            B1[nn][kc] = bb;
        }
    }
    {
        int col = wv * 16 + la;
        #pragma unroll
        for (int kc = 0; kc < 4; kc++) {
            int kb = kc * 32 + lb * 8;
            h8 bb;
            #pragma unroll
            for (int j = 0; j < 8; j++) bb[j] = (_Float16)w2[(kb + j) * 64 + col];
            B2[kc] = bb;
        }
    }
    const float b1v0 = b1[wv * 32 + la];
    const float b1v1 = b1[wv * 32 + 16 + la];
    const float b2v  = b2[wv * 16 + la];

    __syncthreads();

    // ---- layer 1: D[64][128] += x(hi+lo) . W1h ----
    f4v acc[4][2];
    #pragma unroll
    for (int r = 0; r < 4; r++) {
        f4v z = {0.f, 0.f, 0.f, 0.f};
        acc[r][0] = z; acc[r][1] = z;
    }
    #pragma unroll
    for (int r = 0; r < 4; r++) {
        h8 Ah[4], Al[4];
        #pragma unroll
        for (int kc = 0; kc < 4; kc++) {
            Ah[kc] = *(const h8*)&xh[r * 16 + la][kc * 32 + lb * 8];
            Al[kc] = *(const h8*)&xl[r * 16 + la][kc * 32 + lb * 8];
        }
        #pragma unroll
        for (int nn = 0; nn < 2; nn++) {
            #pragma unroll
            for (int kc = 0; kc < 4; kc++) {
                acc[r][nn] = __builtin_amdgcn_mfma_f32_16x16x32_f16(Ah[kc], B1[nn][kc], acc[r][nn], 0, 0, 0);
                acc[r][nn] = __builtin_amdgcn_mfma_f32_16x16x32_f16(Al[kc], B1[nn][kc], acc[r][nn], 0, 0, 0);
            }
        }
    }
    __syncthreads();   // all waves done reading x

    // ---- bias + relu, write h (hi/lo) into xh/xl ----
    #pragma unroll
    for (int r = 0; r < 4; r++) {
        #pragma unroll
        for (int nn = 0; nn < 2; nn++) {
            const float bv = nn ? b1v1 : b1v0;
            const int col = wv * 32 + nn * 16 + la;
            #pragma unroll
            for (int i = 0; i < 4; i++) {
                float h = fmaxf(acc[r][nn][i] + bv, 0.f);
                int row = r * 16 + lb * 4 + i;
                _Float16 hh = (_Float16)h;
                xh[row][col] = hh;
                xl[row][col] = (_Float16)(h - (float)hh);
            }
        }
    }
    __syncthreads();

    // ---- layer 2: Y[64][64] = h(hi+lo) . W2h + b2 ----
    f4v acc2[4];
    #pragma unroll
    for (int r = 0; r < 4; r++) { f4v z = {0.f, 0.f, 0.f, 0.f}; acc2[r] = z; }
    #pragma unroll
    for (int r = 0; r < 4; r++) {
        h8 Ah[4], Al[4];
        #pragma unroll
        for (int kc = 0; kc < 4; kc++) {
            Ah[kc] = *(const h8*)&xh[r * 16 + la][kc * 32 + lb * 8];
            Al[kc] = *(const h8*)&xl[r * 16 + la][kc * 32 + lb * 8];
        }
        #pragma unroll
        for (int kc = 0; kc < 4; kc++) {
            acc2[r] = __builtin_amdgcn_mfma_f32_16x16x32_f16(Ah[kc], B2[kc], acc2[r], 0, 0, 0);
            acc2[r] = __builtin_amdgcn_mfma_f32_16x16x32_f16(Al[kc], B2[kc], acc2[r], 0, 0, 0);
        }
    }

    // ---- store fp32 canonical + fp16 mirror ----
    {
        const int col = wv * 16 + la;
        #pragma unroll
        for (int r = 0; r < 4; r++) {
            #pragma unroll
            for (int i = 0; i < 4; i++) {
                int row = r * 16 + lb * 4 + i;
                if (row < rem) {
                    float y = acc2[r][i] + b2v;
                    size_t idx = (size_t)(base + row) * 64 + col;
                    feat[idx] = y;
                    mirror[idx] = __float2half_rn(y);
                }
            }
        }
    }
}

// ---------------- output MLP: 64 -> 128 relu -> 16, sigmoid, 64-row tiles (fp32) ----------------
__global__ __launch_bounds__(256) void k_out2(const float* __restrict__ vars, float* __restrict__ out, int V,
                                              const float* __restrict__ w1, const float* __restrict__ b1,
                                              const float* __restrict__ w2, const float* __restrict__ b2) {
    __shared__ float xs[64][68];    // [k][row]
    __shared__ float hs[64][132];   // [row][hidden]
    const int t = threadIdx.x;
    const int base = blockIdx.x * 64;
    const int rem = V - base;

    {
        const float4* v4 = (const float4*)(vars + (size_t)base * 64);
        #pragma unroll
        for (int j = 0; j < 4; j++) {
            int idx = j * 256 + t;
            int row = idx >> 4;
            int kq  = idx & 15;
            float4 v = (row < rem) ? v4[row * 16 + kq] : make_float4(0, 0, 0, 0);
            xs[kq * 4 + 0][row] = v.x; xs[kq * 4 + 1][row] = v.y;
            xs[kq * 4 + 2][row] = v.z; xs[kq * 4 + 3][row] = v.w;
        }
    }
    __syncthreads();

    const int tx = t & 31, ty = t >> 5;
    {
        float4 bb = ld4(b1 + tx * 4);
        float4 acc[8];
        #pragma unroll
        for (int r = 0; r < 8; r++) acc[r] = bb;
        const float* w1p = w1 + tx * 4;
        #pragma unroll 4
        for (int k = 0; k < 64; k++) {
            float4 w  = ld4(w1p + k * 128);
            float4 xa = ld4(&xs[k][ty * 8]);
            float4 xb = ld4(&xs[k][ty * 8 + 4]);
            fma4(acc[0], xa.x, w); fma4(acc[1], xa.y, w);
            fma4(acc[2], xa.z, w); fma4(acc[3], xa.w, w);
            fma4(acc[4], xb.x, w); fma4(acc[5], xb.y, w);
            fma4(acc[6], xb.z, w); fma4(acc[7], xb.w, w);
        }
        #pragma unroll
        for (int r = 0; r < 8; r++) {
            float4 h;
            h.x = fmaxf(acc[r].x, 0.f); h.y = fmaxf(acc[r].y, 0.f);
            h.z = fmaxf(acc[r].z, 0.f); h.w = fmaxf(acc[r].w, 0.f);
            st4(&hs[ty * 8 + r][tx * 4], h);
        }
    }
    __syncthreads();

    const int tx3 = t & 3, ty3 = t >> 2;
    {
        float4 o = ld4(b2 + tx3 * 4);
        const float* w2p = w2 + tx3 * 4;
        #pragma unroll 4
        for (int k = 0; k < 128; k++) {
            float4 w = ld4(w2p + k * 16);
            fma4(o, hs[ty3][k], w);
        }
        o.x = 1.f / (1.f + __expf(-o.x));
        o.y = 1.f / (1.f + __expf(-o.y));
        o.z = 1.f / (1.f + __expf(-o.z));
        o.w = 1.f / (1.f + __expf(-o.w));
        if (ty3 < rem) st4(&out[(size_t)(base + ty3) * 16 + tx3 * 4], o);
    }
}

// ---------------- launch ----------------

extern "C" void kernel_launch(void* const* d_in, const int* in_sizes, int n_in,
                              void* d_out, int out_size, void* d_ws, size_t ws_size,
                              hipStream_t stream) {
    const int*   row_idx = (const int*)d_in[0];
    const int*   col_idx = (const int*)d_in[1];
    const float* adj     = (const float*)d_in[2];
    const float* cond    = (const float*)d_in[3];
    const float* pc_w1  = (const float*)d_in[6];
    const float* pc_b1  = (const float*)d_in[7];
    const float* pc_w2  = (const float*)d_in[8];
    const float* pc_b2  = (const float*)d_in[9];
    const float* cu_w1  = (const float*)d_in[10];
    const float* cu_b1  = (const float*)d_in[11];
    const float* cu_w2  = (const float*)d_in[12];
    const float* cu_b2  = (const float*)d_in[13];
    const float* vu_w1  = (const float*)d_in[14];
    const float* vu_b1  = (const float*)d_in[15];
    const float* vu_w2  = (const float*)d_in[16];
    const float* vu_b2  = (const float*)d_in[17];
    const float* out_w1 = (const float*)d_in[18];
    const float* out_b1 = (const float*)d_in[19];
    const float* out_w2 = (const float*)d_in[20];
    const float* out_b2 = (const float*)d_in[21];

    const int NNZ = in_sizes[0];
    const int C   = in_sizes[3];
    const int V   = out_size / 16;

    const int NBc = (C + GB_D - 1) / GB_D;
    const int NBv = (V + GB_D - 1) / GB_D;
    const int NBT = NBc + NBv;

    float* out = (float*)d_out;

    // ---- workspace carve ----
    char* wsb = (char*)d_ws;
    size_t off = 0;
    auto carve = [&](size_t bytes) -> void* {
        void* p = wsb + off;
        off = (off + bytes + 255) & ~(size_t)255;
        return p;
    };
    float*  variables   = (float*)carve((size_t)V * 64 * 4);
    float*  constraints = (float*)carve((size_t)C * 64 * 4);
    float*  v2c         = (float*)carve((size_t)C * 64 * 4);
    float*  c2v         = (float*)carve((size_t)V * 64 * 4);
    __half* var_h       = (__half*)carve((size_t)V * 64 * 2);
    __half* con_h       = (__half*)carve((size_t)C * 64 * 2);
    int2*   pack        = (int2*)carve((size_t)2 * NNZ * 8);
    int*    bcnt        = (int*)carve((size_t)NBT * 4);
    int*    bptr        = (int*)carve((size_t)(NBT + 1) * 4);
    int*    bnxt        = (int*)carve((size_t)NBT * 4);
    int*    dptr_c      = (int*)carve((size_t)(C + 1) * 4);
    int*    dptr_v      = (int*)carve((size_t)(V + 1) * 4);
    (void)ws_size; (void)n_in;

    const size_t shmem = (size_t)NBT * 4;

    // ---- bucket-grouped, destination-sorted edge build ----
    hipMemsetAsync(bcnt, 0, (size_t)NBT * 4, stream);
    k_bhist<<<256, 256, shmem, stream>>>(row_idx, col_idx, NNZ, bcnt, NBc, NBT);
    k_bscan<<<1, 1024, 0, stream>>>(bcnt, NBT, bptr, bnxt);
    k_mpsplit<<<(NNZ + MS_CH - 1) / MS_CH, 256, shmem, stream>>>(row_idx, col_idx, adj, NNZ,
                                                                 bnxt, pack, NBc, NBT);
    k_bsort<<<NBT, 256, 0, stream>>>(bptr, pack, dptr_c, C, dptr_v, V, NBc);

    // ---- init features ----
    k_ones2<<<2048, 256, 0, stream>>>((float4*)variables, V * 16, (uint4*)var_h, V * 8);
    k_pc2<<<(C + 63) / 64, 256, 0, stream>>>(cond, constraints, con_h, C, pc_w1, pc_b1, pc_w2, pc_b2);

    // ---- message-passing rounds ----
    for (int p = 0; p < 3; p++) {
        k_gather<<<2048, 256, 0, stream>>>(dptr_c, pack, var_h, v2c, C);
        k_mlp3<<<(C + 63) / 64, 256, 0, stream>>>(constraints, v2c, con_h, C, cu_w1, cu_b1, cu_w2, cu_b2);
        k_gather<<<2048, 256, 0, stream>>>(dptr_v, pack, con_h, c2v, V);
        k_mlp3<<<(V + 63) / 64, 256, 0, stream>>>(variables, c2v, var_h, V, vu_w1, vu_b1, vu_w2, vu_b2);
    }

    // ---- output ----
    k_out2<<<(V + 63) / 64, 256, 0, stream>>>(variables, out, V, out_w1, out_b1, out_w2, out_b2);
}

// Round 9
// 823.199 us; speedup vs baseline: 1.1043x; 1.1043x over previous
//
#include <hip/hip_runtime.h>
#include <hip/hip_fp16.h>

typedef unsigned int uint;

#define GB_D 64           // destinations per bucket
#define MS_CH 8192        // edges per multisplit block (245 blocks -> keeps CUs busy)
#define BS_CAP 6912       // max edges staged per bucket in k_bsort LDS

using h8  = __attribute__((ext_vector_type(8))) _Float16;
using h4  = __attribute__((ext_vector_type(4))) _Float16;
using f4v = __attribute__((ext_vector_type(4))) float;

__device__ __forceinline__ float4 ld4(const float* p) { return *reinterpret_cast<const float4*>(p); }
__device__ __forceinline__ void st4(float* p, float4 v) { *reinterpret_cast<float4*>(p) = v; }
__device__ __forceinline__ void fma4(float4& a, float s, const float4 w) {
    a.x = fmaf(s, w.x, a.x); a.y = fmaf(s, w.y, a.y);
    a.z = fmaf(s, w.z, a.z); a.w = fmaf(s, w.w, a.w);
}
__device__ __forceinline__ uint pk2(float a, float b) {
    __half2 h = __floats2half2_rn(a, b);
    return *reinterpret_cast<uint*>(&h);
}

// ---------------- bucket histogram (both directions fused) ----------------
__global__ __launch_bounds__(256) void k_bhist(const int* __restrict__ row, const int* __restrict__ col,
                                               int nnz, int* __restrict__ bcnt, int nbc, int nbt) {
    extern __shared__ int ls[];
    for (int b = threadIdx.x; b < nbt; b += blockDim.x) ls[b] = 0;
    __syncthreads();
    int i0 = blockIdx.x * blockDim.x + threadIdx.x;
    int stride = gridDim.x * blockDim.x;
    for (int i = i0; i < nnz; i += stride) {
        atomicAdd(&ls[col[i] >> 6], 1);
        atomicAdd(&ls[nbc + (row[i] >> 6)], 1);
    }
    __syncthreads();
    for (int b = threadIdx.x; b < nbt; b += blockDim.x) {
        int c = ls[b];
        if (c) atomicAdd(&bcnt[b], c);
    }
}

// ---------------- single-block exclusive scan over nbt buckets ----------------
__global__ __launch_bounds__(1024) void k_bscan(const int* __restrict__ cnt, int n,
                                                int* __restrict__ ptr, int* __restrict__ nxt) {
    __shared__ int wsum[17];
    __shared__ int carry, tot;
    if (threadIdx.x == 0) carry = 0;
    __syncthreads();
    int lane = threadIdx.x & 63;
    int wid  = threadIdx.x >> 6;
    for (int base = 0; base < n; base += 1024) {
        int idx = base + (int)threadIdx.x;
        int v = (idx < n) ? cnt[idx] : 0;
        int inc = v;
        #pragma unroll
        for (int off = 1; off < 64; off <<= 1) {
            int t = __shfl_up(inc, (unsigned)off, 64);
            if (lane >= off) inc += t;
        }
        if (lane == 63) wsum[wid] = inc;
        __syncthreads();
        if (threadIdx.x == 0) {
            int s = 0;
            for (int w = 0; w < 16; w++) { int t = wsum[w]; wsum[w] = s; s += t; }
            tot = s;
        }
        __syncthreads();
        int excl = carry + wsum[wid] + (inc - v);
        if (idx < n) { ptr[idx] = excl; nxt[idx] = excl; }
        __syncthreads();
        if (threadIdx.x == 0) carry += tot;
        __syncthreads();
    }
    if (threadIdx.x == 0) ptr[n] = carry;
}

// ---------------- multisplit scatter into bucket-grouped edge array ----------------
// pack.x = (dest&63)<<20 | src ; pack.y = f32 bits of |adj|
__global__ __launch_bounds__(256) void k_mpsplit(const int* __restrict__ row, const int* __restrict__ col,
                                                 const float* __restrict__ adj, int nnz,
                                                 int* __restrict__ bnxt, int2* __restrict__ pack,
                                                 int nbc, int nbt) {
    extern __shared__ int ls[];
    const int t = threadIdx.x;
    for (int b = t; b < nbt; b += 256) ls[b] = 0;
    __syncthreads();
    const int start = blockIdx.x * MS_CH;
    const int end = min(start + MS_CH, nnz);
    for (int i = start + t; i < end; i += 256) {
        atomicAdd(&ls[col[i] >> 6], 1);
        atomicAdd(&ls[nbc + (row[i] >> 6)], 1);
    }
    __syncthreads();
    for (int b = t; b < nbt; b += 256) {
        int c = ls[b];
        ls[b] = c ? atomicAdd(&bnxt[b], c) : 0;
    }
    __syncthreads();
    for (int i = start + t; i < end; i += 256) {
        int r = row[i], c = col[i];
        int vb = __float_as_int(fabsf(adj[i]));
        int p1 = atomicAdd(&ls[c >> 6], 1);
        pack[p1] = make_int2(((c & 63) << 20) | r, vb);
        int p2 = atomicAdd(&ls[nbc + (r >> 6)], 1);
        pack[p2] = make_int2(((r & 63) << 20) | c, vb);
    }
}

// ---------------- in-bucket counting sort (in place via LDS staging) + per-dest ptr ----------------
__global__ __launch_bounds__(256) void k_bsort(const int* __restrict__ bptr, int2* __restrict__ pack,
                                               int* __restrict__ dptr_c, int C,
                                               int* __restrict__ dptr_v, int V, int nbc) {
    __shared__ int2 ebuf[BS_CAP];
    __shared__ int h[GB_D];
    __shared__ int cur[GB_D];
    const int b = blockIdx.x, t = threadIdx.x;
    const int s = bptr[b], e = bptr[b + 1];
    const int n = min(e - s, BS_CAP);
    if (t < GB_D) h[t] = 0;
    __syncthreads();
    for (int i = t; i < n; i += 256) {
        int2 ed = pack[s + i];
        ebuf[i] = ed;
        atomicAdd(&h[((uint)ed.x) >> 20], 1);
    }
    __syncthreads();
    if (t < GB_D) {
        int v = h[t];
        int inc = v;
        #pragma unroll
        for (int off = 1; off < 64; off <<= 1) {
            int u = __shfl_up(inc, (unsigned)off, 64);
            if (t >= off) inc += u;
        }
        int excl = inc - v;
        cur[t] = excl;
        const bool isC = (b < nbc);
        const int base = (isC ? b : b - nbc) << 6;
        const int nd   = isC ? C : V;
        int* dp        = isC ? dptr_c : dptr_v;
        const int d = base + t;
        if (d < nd) dp[d] = s + excl;
        if (d == nd - 1) dp[nd] = s + n;
    }
    __syncthreads();
    for (int i = t; i < n; i += 256) {
        int2 ed = ebuf[i];
        int p = atomicAdd(&cur[((uint)ed.x) >> 20], 1);
        pack[s + p] = make_int2(ed.x & 0xFFFFF, ed.y);
    }
}

// ---------------- gather: one wave per destination, fp16 mirror source, 8-deep ILP ----------------
__global__ __launch_bounds__(256) void k_gather(const int* __restrict__ dptr,
                                                const int2* __restrict__ es,
                                                const __half* __restrict__ sfeat,
                                                float* __restrict__ dmsg, int n) {
    int wid = (int)((blockIdx.x * blockDim.x + threadIdx.x) >> 6);
    int lane = threadIdx.x & 63;
    int nw = (int)((gridDim.x * blockDim.x) >> 6);
    for (int d = wid; d < n; d += nw) {
        int s = dptr[d], e = dptr[d + 1];
        float a0 = 0.f, a1 = 0.f, a2 = 0.f, a3 = 0.f;
        float a4 = 0.f, a5 = 0.f, a6 = 0.f, a7 = 0.f;
        int i = s;
        for (; i + 7 < e; i += 8) {
            int2 e0 = es[i],     e1 = es[i + 1], e2 = es[i + 2], e3 = es[i + 3];
            int2 e4 = es[i + 4], e5 = es[i + 5], e6 = es[i + 6], e7 = es[i + 7];
            a0 = fmaf(__int_as_float(e0.y), __half2float(sfeat[(size_t)e0.x * 64 + lane]), a0);
            a1 = fmaf(__int_as_float(e1.y), __half2float(sfeat[(size_t)e1.x * 64 + lane]), a1);
            a2 = fmaf(__int_as_float(e2.y), __half2float(sfeat[(size_t)e2.x * 64 + lane]), a2);
            a3 = fmaf(__int_as_float(e3.y), __half2float(sfeat[(size_t)e3.x * 64 + lane]), a3);
            a4 = fmaf(__int_as_float(e4.y), __half2float(sfeat[(size_t)e4.x * 64 + lane]), a4);
            a5 = fmaf(__int_as_float(e5.y), __half2float(sfeat[(size_t)e5.x * 64 + lane]), a5);
            a6 = fmaf(__int_as_float(e6.y), __half2float(sfeat[(size_t)e6.x * 64 + lane]), a6);
            a7 = fmaf(__int_as_float(e7.y), __half2float(sfeat[(size_t)e7.x * 64 + lane]), a7);
        }
        for (; i + 1 < e; i += 2) {
            int2 e0 = es[i], e1 = es[i + 1];
            a0 = fmaf(__int_as_float(e0.y), __half2float(sfeat[(size_t)e0.x * 64 + lane]), a0);
            a1 = fmaf(__int_as_float(e1.y), __half2float(sfeat[(size_t)e1.x * 64 + lane]), a1);
        }
        if (i < e) {
            int2 e0 = es[i];
            a0 = fmaf(__int_as_float(e0.y), __half2float(sfeat[(size_t)e0.x * 64 + lane]), a0);
        }
        dmsg[(size_t)d * 64 + lane] = ((a0 + a1) + (a2 + a3)) + ((a4 + a5) + (a6 + a7));
    }
}

// ---------------- feature init: fp32 ones + fp16 mirror ones ----------------
__global__ __launch_bounds__(256) void k_ones2(float4* p, int n4, uint4* ph, int n4h) {
    int i0 = blockIdx.x * blockDim.x + threadIdx.x;
    int stride = gridDim.x * blockDim.x;
    float4 one = make_float4(1.f, 1.f, 1.f, 1.f);
    uint4 oneh = make_uint4(0x3C003C00u, 0x3C003C00u, 0x3C003C00u, 0x3C003C00u);
    for (int i = i0; i < n4; i += stride) p[i] = one;
    for (int i = i0; i < n4h; i += stride) ph[i] = oneh;
}

// ---------------- prepare_cond: 1 -> 128 relu -> 64 (fp32 + fp16 mirror) ----------------
__global__ __launch_bounds__(256) void k_pc2(const float* __restrict__ cond, float* __restrict__ constraints,
                                             __half* __restrict__ conh, int C,
                                             const float* __restrict__ w1, const float* __restrict__ b1,
                                             const float* __restrict__ w2, const float* __restrict__ b2) {
    __shared__ float hs[64][132];
    __shared__ float cs[64];
    const int t = threadIdx.x;
    const int base = blockIdx.x * 64;
    const int rem = C - base;

    if (t < 64) cs[t] = (t < rem) ? cond[base + t] : 0.f;
    __syncthreads();

    #pragma unroll
    for (int j = 0; j < 32; j++) {
        int idx = j * 256 + t;
        int k = idx & 127, row = idx >> 7;
        hs[row][k] = fmaxf(fmaf(cs[row], w1[k], b1[k]), 0.f);
    }
    __syncthreads();

    const int tx2 = t & 15, ty2 = t >> 4;
    float4 bb = ld4(b2 + tx2 * 4);
    float4 acc[4] = { bb, bb, bb, bb };
    const float* w2p = w2 + tx2 * 4;
    #pragma unroll 4
    for (int k = 0; k < 128; k++) {
        float4 w = ld4(w2p + k * 64);
        fma4(acc[0], hs[ty2 * 4 + 0][k], w);
        fma4(acc[1], hs[ty2 * 4 + 1][k], w);
        fma4(acc[2], hs[ty2 * 4 + 2][k], w);
        fma4(acc[3], hs[ty2 * 4 + 3][k], w);
    }
    #pragma unroll
    for (int r = 0; r < 4; r++) {
        int row = ty2 * 4 + r;
        if (row < rem) {
            st4(&constraints[(size_t)(base + row) * 64 + tx2 * 4], acc[r]);
            uint2 o;
            o.x = pk2(acc[r].x, acc[r].y);
            o.y = pk2(acc[r].z, acc[r].w);
            *(uint2*)(conh + (size_t)(base + row) * 64 + tx2 * 4) = o;
        }
    }
}

// ---------------- update MLP via MFMA: concat(feat,msg)[128] -> 128 relu -> 64, in-place ----------------
__global__ __launch_bounds__(256) void k_mlp3(float* __restrict__ feat, const float* __restrict__ msg,
                                              __half* __restrict__ mirror, int n,
                                              const float* __restrict__ w1, const float* __restrict__ b1,
                                              const float* __restrict__ w2, const float* __restrict__ b2) {
    __shared__ _Float16 xh[64][136];   // x (later h) hi
    __shared__ _Float16 xl[64][136];   // x (later h) lo
    const int t = threadIdx.x;
    const int base = blockIdx.x * 64;
    const int rem = n - base;
    const int wv = t >> 6;            // wave 0..3
    const int la = t & 15;            // lane&15  : A-row / B-col / D-col index
    const int lb = (t & 63) >> 4;     // lane>>4  : k-chunk / D-row group

    // ---- stage x = concat(feat,msg) as fp16 hi + lo ----
    {
        const float4* f4p = (const float4*)(feat + (size_t)base * 64);
        const float4* m4p = (const float4*)(msg + (size_t)base * 64);
        #pragma unroll
        for (int j = 0; j < 8; j++) {
            int idx = j * 256 + t;          // 0..2047
            int row = idx >> 5;             // 0..63
            int q   = idx & 31;             // 0..31
            float4 v = make_float4(0.f, 0.f, 0.f, 0.f);
            if (row < rem) v = (q < 16) ? f4p[row * 16 + q] : m4p[row * 16 + (q - 16)];
            int k = (q < 16) ? q * 4 : 64 + (q - 16) * 4;
            h4 hi, lo;
            hi[0] = (_Float16)v.x; lo[0] = (_Float16)(v.x - (float)hi[0]);
            hi[1] = (_Float16)v.y; lo[1] = (_Float16)(v.y - (float)hi[1]);
            hi[2] = (_Float16)v.z; lo[2] = (_Float16)(v.z - (float)hi[2]);
            hi[3] = (_Float16)v.w; lo[3] = (_Float16)(v.w - (float)hi[3]);
            *(h4*)&xh[row][k] = hi;
            *(h4*)&xl[row][k] = lo;
        }
    }

    // ---- weight fragments (fp16) into registers ----
    h8 B1[2][4];
    h8 B2[4];
    #pragma unroll
    for (int nn = 0; nn < 2; nn++) {
        int col = wv * 32 + nn * 16 + la;
        #pragma unroll
        for (int kc = 0; kc < 4; kc++) {
            int kb = kc * 32 + lb * 8;
            h8 bb;
            #pragma unroll
            for (int j = 0; j < 8; j++) bb[j] = (_Float16)w1[(kb + j) * 128 + col];
            B1[nn][kc] = bb;
        }
    }
    {
        int col = wv * 16 + la;
        #pragma unroll
        for (int kc = 0; kc < 4; kc++) {
            int kb = kc * 32 + lb * 8;
            h8 bb;
            #pragma unroll
            for (int j = 0; j < 8; j++) bb[j] = (_Float16)w2[(kb + j) * 64 + col];
            B2[kc] = bb;
        }
    }
    const float b1v0 = b1[wv * 32 + la];
    const float b1v1 = b1[wv * 32 + 16 + la];
    const float b2v  = b2[wv * 16 + la];

    __syncthreads();

    // ---- layer 1 ----
    f4v acc[4][2];
    #pragma unroll
    for (int r = 0; r < 4; r++) {
        f4v z = {0.f, 0.f, 0.f, 0.f};
        acc[r][0] = z; acc[r][1] = z;
    }
    #pragma unroll
    for (int r = 0; r < 4; r++) {
        h8 Ah[4], Al[4];
        #pragma unroll
        for (int kc = 0; kc < 4; kc++) {
            Ah[kc] = *(const h8*)&xh[r * 16 + la][kc * 32 + lb * 8];
            Al[kc] = *(const h8*)&xl[r * 16 + la][kc * 32 + lb * 8];
        }
        #pragma unroll
        for (int nn = 0; nn < 2; nn++) {
            #pragma unroll
            for (int kc = 0; kc < 4; kc++) {
                acc[r][nn] = __builtin_amdgcn_mfma_f32_16x16x32_f16(Ah[kc], B1[nn][kc], acc[r][nn], 0, 0, 0);
                acc[r][nn] = __builtin_amdgcn_mfma_f32_16x16x32_f16(Al[kc], B1[nn][kc], acc[r][nn], 0, 0, 0);
            }
        }
    }
    __syncthreads();

    // ---- bias + relu, write h (hi/lo) ----
    #pragma unroll
    for (int r = 0; r < 4; r++) {
        #pragma unroll
        for (int nn = 0; nn < 2; nn++) {
            const float bv = nn ? b1v1 : b1v0;
            const int col = wv * 32 + nn * 16 + la;
            #pragma unroll
            for (int i = 0; i < 4; i++) {
                float h = fmaxf(acc[r][nn][i] + bv, 0.f);
                int row = r * 16 + lb * 4 + i;
                _Float16 hh = (_Float16)h;
                xh[row][col] = hh;
                xl[row][col] = (_Float16)(h - (float)hh);
            }
        }
    }
    __syncthreads();

    // ---- layer 2 ----
    f4v acc2[4];
    #pragma unroll
    for (int r = 0; r < 4; r++) { f4v z = {0.f, 0.f, 0.f, 0.f}; acc2[r] = z; }
    #pragma unroll
    for (int r = 0; r < 4; r++) {
        h8 Ah[4], Al[4];
        #pragma unroll
        for (int kc = 0; kc < 4; kc++) {
            Ah[kc] = *(const h8*)&xh[r * 16 + la][kc * 32 + lb * 8];
            Al[kc] = *(const h8*)&xl[r * 16 + la][kc * 32 + lb * 8];
        }
        #pragma unroll
        for (int kc = 0; kc < 4; kc++) {
            acc2[r] = __builtin_amdgcn_mfma_f32_16x16x32_f16(Ah[kc], B2[kc], acc2[r], 0, 0, 0);
            acc2[r] = __builtin_amdgcn_mfma_f32_16x16x32_f16(Al[kc], B2[kc], acc2[r], 0, 0, 0);
        }
    }

    // ---- store fp32 canonical + fp16 mirror ----
    {
        const int col = wv * 16 + la;
        #pragma unroll
        for (int r = 0; r < 4; r++) {
            #pragma unroll
            for (int i = 0; i < 4; i++) {
                int row = r * 16 + lb * 4 + i;
                if (row < rem) {
                    float y = acc2[r][i] + b2v;
                    size_t idx = (size_t)(base + row) * 64 + col;
                    feat[idx] = y;
                    mirror[idx] = __float2half_rn(y);
                }
            }
        }
    }
}

// ---------------- output MLP via MFMA: 64 -> 128 relu -> 16, sigmoid ----------------
// Same hi/lo fp16 MFMA pattern as k_mlp3. 64-row tile, 4 waves.
__global__ __launch_bounds__(256) void k_out3(const float* __restrict__ vars, float* __restrict__ out, int V,
                                              const float* __restrict__ w1, const float* __restrict__ b1,
                                              const float* __restrict__ w2, const float* __restrict__ b2) {
    __shared__ _Float16 xh[64][136];   // x: cols 0..63 used; h: cols 0..127
    __shared__ _Float16 xl[64][136];
    const int t = threadIdx.x;
    const int base = blockIdx.x * 64;
    const int rem = V - base;
    const int wv = t >> 6;
    const int la = t & 15;
    const int lb = (t & 63) >> 4;

    // ---- stage x[64][64] hi/lo ----
    {
        const float4* v4p = (const float4*)(vars + (size_t)base * 64);
        #pragma unroll
        for (int j = 0; j < 4; j++) {
            int idx = j * 256 + t;          // 0..1023
            int row = idx >> 4;             // 0..63
            int q   = idx & 15;             // 0..15
            float4 v = make_float4(0.f, 0.f, 0.f, 0.f);
            if (row < rem) v = v4p[row * 16 + q];
            int k = q * 4;
            h4 hi, lo;
            hi[0] = (_Float16)v.x; lo[0] = (_Float16)(v.x - (float)hi[0]);
            hi[1] = (_Float16)v.y; lo[1] = (_Float16)(v.y - (float)hi[1]);
            hi[2] = (_Float16)v.z; lo[2] = (_Float16)(v.z - (float)hi[2]);
            hi[3] = (_Float16)v.w; lo[3] = (_Float16)(v.w - (float)hi[3]);
            *(h4*)&xh[row][k] = hi;
            *(h4*)&xl[row][k] = lo;
        }
    }

    // ---- weights: layer1 wave has 2 col-tiles x 2 k-chunks (K=64); layer2 1 col-tile x 4 k-chunks (K=128, N=16)
    h8 B1[2][2];
    h8 B2[4];
    #pragma unroll
    for (int nn = 0; nn < 2; nn++) {
        int col = wv * 32 + nn * 16 + la;
        #pragma unroll
        for (int kc = 0; kc < 2; kc++) {
            int kb = kc * 32 + lb * 8;
            h8 bb;
            #pragma unroll
            for (int j = 0; j < 8; j++) bb[j] = (_Float16)w1[(kb + j) * 128 + col];
            B1[nn][kc] = bb;
        }
    }
    {
        int col = la;   // N=16
        #pragma unroll
        for (int kc = 0; kc < 4; kc++) {
            int kb = kc * 32 + lb * 8;
            h8 bb;
            #pragma unroll
            for (int j = 0; j < 8; j++) bb[j] = (_Float16)w2[(kb + j) * 16 + col];
            B2[kc] = bb;
        }
    }
    const float b1v0 = b1[wv * 32 + la];
    const float b1v1 = b1[wv * 32 + 16 + la];
    const float b2v  = b2[la];

    __syncthreads();

    // ---- layer 1: H[64][128] = x(hi+lo).W1, K=64 ----
    f4v acc[4][2];
    #pragma unroll
    for (int r = 0; r < 4; r++) {
        f4v z = {0.f, 0.f, 0.f, 0.f};
        acc[r][0] = z; acc[r][1] = z;
    }
    #pragma unroll
    for (int r = 0; r < 4; r++) {
        h8 Ah[2], Al[2];
        #pragma unroll
        for (int kc = 0; kc < 2; kc++) {
            Ah[kc] = *(const h8*)&xh[r * 16 + la][kc * 32 + lb * 8];
            Al[kc] = *(const h8*)&xl[r * 16 + la][kc * 32 + lb * 8];
        }
        #pragma unroll
        for (int nn = 0; nn < 2; nn++) {
            #pragma unroll
            for (int kc = 0; kc < 2; kc++) {
                acc[r][nn] = __builtin_amdgcn_mfma_f32_16x16x32_f16(Ah[kc], B1[nn][kc], acc[r][nn], 0, 0, 0);
                acc[r][nn] = __builtin_amdgcn_mfma_f32_16x16x32_f16(Al[kc], B1[nn][kc], acc[r][nn], 0, 0, 0);
            }
        }
    }
    __syncthreads();

    // ---- bias + relu -> h hi/lo ----
    #pragma unroll
    for (int r = 0; r < 4; r++) {
        #pragma unroll
        for (int nn = 0; nn < 2; nn++) {
            const float bv = nn ? b1v1 : b1v0;
            const int col = wv * 32 + nn * 16 + la;
            #pragma unroll
            for (int i = 0; i < 4; i++) {
                float h = fmaxf(acc[r][nn][i] + bv, 0.f);
                int row = r * 16 + lb * 4 + i;
                _Float16 hh = (_Float16)h;
                xh[row][col] = hh;
                xl[row][col] = (_Float16)(h - (float)hh);
            }
        }
    }
    __syncthreads();

    // ---- layer 2: y[64][16]; wave wv owns row-tile wv ----
    f4v acc2 = {0.f, 0.f, 0.f, 0.f};
    {
        h8 Ah[4], Al[4];
        #pragma unroll
        for (int kc = 0; kc < 4; kc++) {
            Ah[kc] = *(const h8*)&xh[wv * 16 + la][kc * 32 + lb * 8];
            Al[kc] = *(const h8*)&xl[wv * 16 + la][kc * 32 + lb * 8];
        }
        #pragma unroll
        for (int kc = 0; kc < 4; kc++) {
            acc2 = __builtin_amdgcn_mfma_f32_16x16x32_f16(Ah[kc], B2[kc], acc2, 0, 0, 0);
            acc2 = __builtin_amdgcn_mfma_f32_16x16x32_f16(Al[kc], B2[kc], acc2, 0, 0, 0);
        }
    }

    // ---- sigmoid + store: col = la, row = wv*16 + lb*4 + i ----
    #pragma unroll
    for (int i = 0; i < 4; i++) {
        int row = wv * 16 + lb * 4 + i;
        if (row < rem) {
            float y = acc2[i] + b2v;
            out[(size_t)(base + row) * 16 + la] = 1.f / (1.f + __expf(-y));
        }
    }
}

// ---------------- launch ----------------

extern "C" void kernel_launch(void* const* d_in, const int* in_sizes, int n_in,
                              void* d_out, int out_size, void* d_ws, size_t ws_size,
                              hipStream_t stream) {
    const int*   row_idx = (const int*)d_in[0];
    const int*   col_idx = (const int*)d_in[1];
    const float* adj     = (const float*)d_in[2];
    const float* cond    = (const float*)d_in[3];
    const float* pc_w1  = (const float*)d_in[6];
    const float* pc_b1  = (const float*)d_in[7];
    const float* pc_w2  = (const float*)d_in[8];
    const float* pc_b2  = (const float*)d_in[9];
    const float* cu_w1  = (const float*)d_in[10];
    const float* cu_b1  = (const float*)d_in[11];
    const float* cu_w2  = (const float*)d_in[12];
    const float* cu_b2  = (const float*)d_in[13];
    const float* vu_w1  = (const float*)d_in[14];
    const float* vu_b1  = (const float*)d_in[15];
    const float* vu_w2  = (const float*)d_in[16];
    const float* vu_b2  = (const float*)d_in[17];
    const float* out_w1 = (const float*)d_in[18];
    const float* out_b1 = (const float*)d_in[19];
    const float* out_w2 = (const float*)d_in[20];
    const float* out_b2 = (const float*)d_in[21];

    const int NNZ = in_sizes[0];
    const int C   = in_sizes[3];
    const int V   = out_size / 16;

    const int NBc = (C + GB_D - 1) / GB_D;
    const int NBv = (V + GB_D - 1) / GB_D;
    const int NBT = NBc + NBv;

    float* out = (float*)d_out;

    // ---- workspace carve ----
    char* wsb = (char*)d_ws;
    size_t off = 0;
    auto carve = [&](size_t bytes) -> void* {
        void* p = wsb + off;
        off = (off + bytes + 255) & ~(size_t)255;
        return p;
    };
    float*  variables   = (float*)carve((size_t)V * 64 * 4);
    float*  constraints = (float*)carve((size_t)C * 64 * 4);
    float*  v2c         = (float*)carve((size_t)C * 64 * 4);
    float*  c2v         = (float*)carve((size_t)V * 64 * 4);
    __half* var_h       = (__half*)carve((size_t)V * 64 * 2);
    __half* con_h       = (__half*)carve((size_t)C * 64 * 2);
    int2*   pack        = (int2*)carve((size_t)2 * NNZ * 8);
    int*    bcnt        = (int*)carve((size_t)NBT * 4);
    int*    bptr        = (int*)carve((size_t)(NBT + 1) * 4);
    int*    bnxt        = (int*)carve((size_t)NBT * 4);
    int*    dptr_c      = (int*)carve((size_t)(C + 1) * 4);
    int*    dptr_v      = (int*)carve((size_t)(V + 1) * 4);
    (void)ws_size; (void)n_in;

    const size_t shmem = (size_t)NBT * 4;

    // ---- bucket-grouped, destination-sorted edge build ----
    hipMemsetAsync(bcnt, 0, (size_t)NBT * 4, stream);
    k_bhist<<<256, 256, shmem, stream>>>(row_idx, col_idx, NNZ, bcnt, NBc, NBT);
    k_bscan<<<1, 1024, 0, stream>>>(bcnt, NBT, bptr, bnxt);
    k_mpsplit<<<(NNZ + MS_CH - 1) / MS_CH, 256, shmem, stream>>>(row_idx, col_idx, adj, NNZ,
                                                                 bnxt, pack, NBc, NBT);
    k_bsort<<<NBT, 256, 0, stream>>>(bptr, pack, dptr_c, C, dptr_v, V, NBc);

    // ---- init features ----
    k_ones2<<<2048, 256, 0, stream>>>((float4*)variables, V * 16, (uint4*)var_h, V * 8);
    k_pc2<<<(C + 63) / 64, 256, 0, stream>>>(cond, constraints, con_h, C, pc_w1, pc_b1, pc_w2, pc_b2);

    // ---- message-passing rounds ----
    for (int p = 0; p < 3; p++) {
        k_gather<<<2048, 256, 0, stream>>>(dptr_c, pack, var_h, v2c, C);
        k_mlp3<<<(C + 63) / 64, 256, 0, stream>>>(constraints, v2c, con_h, C, cu_w1, cu_b1, cu_w2, cu_b2);
        k_gather<<<2048, 256, 0, stream>>>(dptr_v, pack, con_h, c2v, V);
        k_mlp3<<<(V + 63) / 64, 256, 0, stream>>>(variables, c2v, var_h, V, vu_w1, vu_b1, vu_w2, vu_b2);
    }

    // ---- output ----
    k_out3<<<(V + 63) / 64, 256, 0, stream>>>(variables, out, V, out_w1, out_b1, out_w2, out_b2);
}

// Round 10
// 760.634 us; speedup vs baseline: 1.1952x; 1.0823x over previous
//
#include <hip/hip_runtime.h>
#include <hip/hip_fp16.h>

typedef unsigned int uint;

#define GB_D 64           // destinations per bucket
#define MS_CH 8192        // edges per multisplit block (245 blocks -> keeps CUs busy)
#define BS_CAP 6912       // max edges staged per bucket in k_bsort LDS

using h8  = __attribute__((ext_vector_type(8))) _Float16;
using h4  = __attribute__((ext_vector_type(4))) _Float16;
using f4v = __attribute__((ext_vector_type(4))) float;

__device__ __forceinline__ float4 ld4(const float* p) { return *reinterpret_cast<const float4*>(p); }
__device__ __forceinline__ void st4(float* p, float4 v) { *reinterpret_cast<float4*>(p) = v; }
__device__ __forceinline__ void fma4(float4& a, float s, const float4 w) {
    a.x = fmaf(s, w.x, a.x); a.y = fmaf(s, w.y, a.y);
    a.z = fmaf(s, w.z, a.z); a.w = fmaf(s, w.w, a.w);
}
__device__ __forceinline__ uint pk2(float a, float b) {
    __half2 h = __floats2half2_rn(a, b);
    return *reinterpret_cast<uint*>(&h);
}

// ---------------- bucket histogram (both directions fused) ----------------
__global__ __launch_bounds__(256) void k_bhist(const int* __restrict__ row, const int* __restrict__ col,
                                               int nnz, int* __restrict__ bcnt, int nbc, int nbt) {
    extern __shared__ int ls[];
    for (int b = threadIdx.x; b < nbt; b += blockDim.x) ls[b] = 0;
    __syncthreads();
    int i0 = blockIdx.x * blockDim.x + threadIdx.x;
    int stride = gridDim.x * blockDim.x;
    for (int i = i0; i < nnz; i += stride) {
        atomicAdd(&ls[col[i] >> 6], 1);
        atomicAdd(&ls[nbc + (row[i] >> 6)], 1);
    }
    __syncthreads();
    for (int b = threadIdx.x; b < nbt; b += blockDim.x) {
        int c = ls[b];
        if (c) atomicAdd(&bcnt[b], c);
    }
}

// ---------------- single-block exclusive scan over nbt buckets ----------------
__global__ __launch_bounds__(1024) void k_bscan(const int* __restrict__ cnt, int n,
                                                int* __restrict__ ptr, int* __restrict__ nxt) {
    __shared__ int wsum[17];
    __shared__ int carry, tot;
    if (threadIdx.x == 0) carry = 0;
    __syncthreads();
    int lane = threadIdx.x & 63;
    int wid  = threadIdx.x >> 6;
    for (int base = 0; base < n; base += 1024) {
        int idx = base + (int)threadIdx.x;
        int v = (idx < n) ? cnt[idx] : 0;
        int inc = v;
        #pragma unroll
        for (int off = 1; off < 64; off <<= 1) {
            int t = __shfl_up(inc, (unsigned)off, 64);
            if (lane >= off) inc += t;
        }
        if (lane == 63) wsum[wid] = inc;
        __syncthreads();
        if (threadIdx.x == 0) {
            int s = 0;
            for (int w = 0; w < 16; w++) { int t = wsum[w]; wsum[w] = s; s += t; }
            tot = s;
        }
        __syncthreads();
        int excl = carry + wsum[wid] + (inc - v);
        if (idx < n) { ptr[idx] = excl; nxt[idx] = excl; }
        __syncthreads();
        if (threadIdx.x == 0) carry += tot;
        __syncthreads();
    }
    if (threadIdx.x == 0) ptr[n] = carry;
}

// ---------------- multisplit scatter into bucket-grouped edge array ----------------
// pack.x = (dest&63)<<20 | src ; pack.y = f32 bits of |adj|
__global__ __launch_bounds__(256) void k_mpsplit(const int* __restrict__ row, const int* __restrict__ col,
                                                 const float* __restrict__ adj, int nnz,
                                                 int* __restrict__ bnxt, int2* __restrict__ pack,
                                                 int nbc, int nbt) {
    extern __shared__ int ls[];
    const int t = threadIdx.x;
    for (int b = t; b < nbt; b += 256) ls[b] = 0;
    __syncthreads();
    const int start = blockIdx.x * MS_CH;
    const int end = min(start + MS_CH, nnz);
    for (int i = start + t; i < end; i += 256) {
        atomicAdd(&ls[col[i] >> 6], 1);
        atomicAdd(&ls[nbc + (row[i] >> 6)], 1);
    }
    __syncthreads();
    for (int b = t; b < nbt; b += 256) {
        int c = ls[b];
        ls[b] = c ? atomicAdd(&bnxt[b], c) : 0;
    }
    __syncthreads();
    for (int i = start + t; i < end; i += 256) {
        int r = row[i], c = col[i];
        int vb = __float_as_int(fabsf(adj[i]));
        int p1 = atomicAdd(&ls[c >> 6], 1);
        pack[p1] = make_int2(((c & 63) << 20) | r, vb);
        int p2 = atomicAdd(&ls[nbc + (r >> 6)], 1);
        pack[p2] = make_int2(((r & 63) << 20) | c, vb);
    }
}

// ---------------- in-bucket counting sort + per-dest ptr + per-dest weight sums ----------------
// One block per bucket. Also emits sumw[c] = sum of |adj| per C-destination (used to replace
// the first C-gather: variables==1 so v2c row == sumw broadcast).
__global__ __launch_bounds__(256) void k_bsort(const int* __restrict__ bptr, int2* __restrict__ pack,
                                               int* __restrict__ dptr_c, int C,
                                               int* __restrict__ dptr_v, int V, int nbc,
                                               float* __restrict__ sumw) {
    __shared__ int2 ebuf[BS_CAP];
    __shared__ int h[GB_D];
    __shared__ int cur[GB_D];
    __shared__ float sw[GB_D];
    const int b = blockIdx.x, t = threadIdx.x;
    const int s = bptr[b], e = bptr[b + 1];
    const int n = min(e - s, BS_CAP);
    if (t < GB_D) { h[t] = 0; sw[t] = 0.f; }
    __syncthreads();
    for (int i = t; i < n; i += 256) {
        int2 ed = pack[s + i];
        ebuf[i] = ed;
        int d = ((uint)ed.x) >> 20;
        atomicAdd(&h[d], 1);
        atomicAdd(&sw[d], __int_as_float(ed.y));
    }
    __syncthreads();
    if (t < GB_D) {
        int v = h[t];
        int inc = v;
        #pragma unroll
        for (int off = 1; off < 64; off <<= 1) {
            int u = __shfl_up(inc, (unsigned)off, 64);
            if (t >= off) inc += u;
        }
        int excl = inc - v;
        cur[t] = excl;
        const bool isC = (b < nbc);
        const int base = (isC ? b : b - nbc) << 6;
        const int nd   = isC ? C : V;
        int* dp        = isC ? dptr_c : dptr_v;
        const int d = base + t;
        if (d < nd) {
            dp[d] = s + excl;
            if (isC) sumw[d] = sw[t];
        }
        if (d == nd - 1) dp[nd] = s + n;
    }
    __syncthreads();
    for (int i = t; i < n; i += 256) {
        int2 ed = ebuf[i];
        int p = atomicAdd(&cur[((uint)ed.x) >> 20], 1);
        pack[s + p] = make_int2(ed.x & 0xFFFFF, ed.y);
    }
}

// ---------------- broadcast per-dest weight sum into message rows (replaces first C-gather) ----------------
__global__ __launch_bounds__(256) void k_bcast(const float* __restrict__ sumw,
                                               float4* __restrict__ dmsg, int n16) {
    int i0 = blockIdx.x * blockDim.x + threadIdx.x;
    int stride = gridDim.x * blockDim.x;
    for (int i = i0; i < n16; i += stride) {
        float v = sumw[i >> 4];
        dmsg[i] = make_float4(v, v, v, v);
    }
}

// ---------------- gather: one wave per destination, fp16 mirror source, 8-deep ILP ----------------
__global__ __launch_bounds__(256) void k_gather(const int* __restrict__ dptr,
                                                const int2* __restrict__ es,
                                                const __half* __restrict__ sfeat,
                                                float* __restrict__ dmsg, int n) {
    int wid = (int)((blockIdx.x * blockDim.x + threadIdx.x) >> 6);
    int lane = threadIdx.x & 63;
    int nw = (int)((gridDim.x * blockDim.x) >> 6);
    for (int d = wid; d < n; d += nw) {
        int s = dptr[d], e = dptr[d + 1];
        float a0 = 0.f, a1 = 0.f, a2 = 0.f, a3 = 0.f;
        float a4 = 0.f, a5 = 0.f, a6 = 0.f, a7 = 0.f;
        int i = s;
        for (; i + 7 < e; i += 8) {
            int2 e0 = es[i],     e1 = es[i + 1], e2 = es[i + 2], e3 = es[i + 3];
            int2 e4 = es[i + 4], e5 = es[i + 5], e6 = es[i + 6], e7 = es[i + 7];
            a0 = fmaf(__int_as_float(e0.y), __half2float(sfeat[(size_t)e0.x * 64 + lane]), a0);
            a1 = fmaf(__int_as_float(e1.y), __half2float(sfeat[(size_t)e1.x * 64 + lane]), a1);
            a2 = fmaf(__int_as_float(e2.y), __half2float(sfeat[(size_t)e2.x * 64 + lane]), a2);
            a3 = fmaf(__int_as_float(e3.y), __half2float(sfeat[(size_t)e3.x * 64 + lane]), a3);
            a4 = fmaf(__int_as_float(e4.y), __half2float(sfeat[(size_t)e4.x * 64 + lane]), a4);
            a5 = fmaf(__int_as_float(e5.y), __half2float(sfeat[(size_t)e5.x * 64 + lane]), a5);
            a6 = fmaf(__int_as_float(e6.y), __half2float(sfeat[(size_t)e6.x * 64 + lane]), a6);
            a7 = fmaf(__int_as_float(e7.y), __half2float(sfeat[(size_t)e7.x * 64 + lane]), a7);
        }
        for (; i + 1 < e; i += 2) {
            int2 e0 = es[i], e1 = es[i + 1];
            a0 = fmaf(__int_as_float(e0.y), __half2float(sfeat[(size_t)e0.x * 64 + lane]), a0);
            a1 = fmaf(__int_as_float(e1.y), __half2float(sfeat[(size_t)e1.x * 64 + lane]), a1);
        }
        if (i < e) {
            int2 e0 = es[i];
            a0 = fmaf(__int_as_float(e0.y), __half2float(sfeat[(size_t)e0.x * 64 + lane]), a0);
        }
        dmsg[(size_t)d * 64 + lane] = ((a0 + a1) + (a2 + a3)) + ((a4 + a5) + (a6 + a7));
    }
}

// ---------------- feature init: fp32 ones (mirror init not needed; overwritten before read) ----------------
__global__ __launch_bounds__(256) void k_ones(float4* p, int n4) {
    int i0 = blockIdx.x * blockDim.x + threadIdx.x;
    int stride = gridDim.x * blockDim.x;
    float4 one = make_float4(1.f, 1.f, 1.f, 1.f);
    for (int i = i0; i < n4; i += stride) p[i] = one;
}

// ---------------- prepare_cond: 1 -> 128 relu -> 64 (fp32 + fp16 mirror) ----------------
__global__ __launch_bounds__(256) void k_pc2(const float* __restrict__ cond, float* __restrict__ constraints,
                                             __half* __restrict__ conh, int C,
                                             const float* __restrict__ w1, const float* __restrict__ b1,
                                             const float* __restrict__ w2, const float* __restrict__ b2) {
    __shared__ float hs[64][132];
    __shared__ float cs[64];
    const int t = threadIdx.x;
    const int base = blockIdx.x * 64;
    const int rem = C - base;

    if (t < 64) cs[t] = (t < rem) ? cond[base + t] : 0.f;
    __syncthreads();

    #pragma unroll
    for (int j = 0; j < 32; j++) {
        int idx = j * 256 + t;
        int k = idx & 127, row = idx >> 7;
        hs[row][k] = fmaxf(fmaf(cs[row], w1[k], b1[k]), 0.f);
    }
    __syncthreads();

    const int tx2 = t & 15, ty2 = t >> 4;
    float4 bb = ld4(b2 + tx2 * 4);
    float4 acc[4] = { bb, bb, bb, bb };
    const float* w2p = w2 + tx2 * 4;
    #pragma unroll 4
    for (int k = 0; k < 128; k++) {
        float4 w = ld4(w2p + k * 64);
        fma4(acc[0], hs[ty2 * 4 + 0][k], w);
        fma4(acc[1], hs[ty2 * 4 + 1][k], w);
        fma4(acc[2], hs[ty2 * 4 + 2][k], w);
        fma4(acc[3], hs[ty2 * 4 + 3][k], w);
    }
    #pragma unroll
    for (int r = 0; r < 4; r++) {
        int row = ty2 * 4 + r;
        if (row < rem) {
            st4(&constraints[(size_t)(base + row) * 64 + tx2 * 4], acc[r]);
            uint2 o;
            o.x = pk2(acc[r].x, acc[r].y);
            o.y = pk2(acc[r].z, acc[r].w);
            *(uint2*)(conh + (size_t)(base + row) * 64 + tx2 * 4) = o;
        }
    }
}

// ---------------- update MLP via MFMA: concat(feat,msg)[128] -> 128 relu -> 64, in-place ----------------
__global__ __launch_bounds__(256) void k_mlp3(float* __restrict__ feat, const float* __restrict__ msg,
                                              __half* __restrict__ mirror, int n,
                                              const float* __restrict__ w1, const float* __restrict__ b1,
                                              const float* __restrict__ w2, const float* __restrict__ b2) {
    __shared__ _Float16 xh[64][136];   // x (later h) hi
    __shared__ _Float16 xl[64][136];   // x (later h) lo
    const int t = threadIdx.x;
    const int base = blockIdx.x * 64;
    const int rem = n - base;
    const int wv = t >> 6;            // wave 0..3
    const int la = t & 15;            // lane&15  : A-row / B-col / D-col index
    const int lb = (t & 63) >> 4;     // lane>>4  : k-chunk / D-row group

    // ---- stage x = concat(feat,msg) as fp16 hi + lo ----
    {
        const float4* f4p = (const float4*)(feat + (size_t)base * 64);
        const float4* m4p = (const float4*)(msg + (size_t)base * 64);
        #pragma unroll
        for (int j = 0; j < 8; j++) {
            int idx = j * 256 + t;          // 0..2047
            int row = idx >> 5;             // 0..63
            int q   = idx & 31;             // 0..31
            float4 v = make_float4(0.f, 0.f, 0.f, 0.f);
            if (row < rem) v = (q < 16) ? f4p[row * 16 + q] : m4p[row * 16 + (q - 16)];
            int k = (q < 16) ? q * 4 : 64 + (q - 16) * 4;
            h4 hi, lo;
            hi[0] = (_Float16)v.x; lo[0] = (_Float16)(v.x - (float)hi[0]);
            hi[1] = (_Float16)v.y; lo[1] = (_Float16)(v.y - (float)hi[1]);
            hi[2] = (_Float16)v.z; lo[2] = (_Float16)(v.z - (float)hi[2]);
            hi[3] = (_Float16)v.w; lo[3] = (_Float16)(v.w - (float)hi[3]);
            *(h4*)&xh[row][k] = hi;
            *(h4*)&xl[row][k] = lo;
        }
    }

    // ---- weight fragments (fp16) into registers ----
    h8 B1[2][4];
    h8 B2[4];
    #pragma unroll
    for (int nn = 0; nn < 2; nn++) {
        int col = wv * 32 + nn * 16 + la;
        #pragma unroll
        for (int kc = 0; kc < 4; kc++) {
            int kb = kc * 32 + lb * 8;
            h8 bb;
            #pragma unroll
            for (int j = 0; j < 8; j++) bb[j] = (_Float16)w1[(kb + j) * 128 + col];
            B1[nn][kc] = bb;
        }
    }
    {
        int col = wv * 16 + la;
        #pragma unroll
        for (int kc = 0; kc < 4; kc++) {
            int kb = kc * 32 + lb * 8;
            h8 bb;
            #pragma unroll
            for (int j = 0; j < 8; j++) bb[j] = (_Float16)w2[(kb + j) * 64 + col];
            B2[kc] = bb;
        }
    }
    const float b1v0 = b1[wv * 32 + la];
    const float b1v1 = b1[wv * 32 + 16 + la];
    const float b2v  = b2[wv * 16 + la];

    __syncthreads();

    // ---- layer 1 ----
    f4v acc[4][2];
    #pragma unroll
    for (int r = 0; r < 4; r++) {
        f4v z = {0.f, 0.f, 0.f, 0.f};
        acc[r][0] = z; acc[r][1] = z;
    }
    #pragma unroll
    for (int r = 0; r < 4; r++) {
        h8 Ah[4], Al[4];
        #pragma unroll
        for (int kc = 0; kc < 4; kc++) {
            Ah[kc] = *(const h8*)&xh[r * 16 + la][kc * 32 + lb * 8];
            Al[kc] = *(const h8*)&xl[r * 16 + la][kc * 32 + lb * 8];
        }
        #pragma unroll
        for (int nn = 0; nn < 2; nn++) {
            #pragma unroll
            for (int kc = 0; kc < 4; kc++) {
                acc[r][nn] = __builtin_amdgcn_mfma_f32_16x16x32_f16(Ah[kc], B1[nn][kc], acc[r][nn], 0, 0, 0);
                acc[r][nn] = __builtin_amdgcn_mfma_f32_16x16x32_f16(Al[kc], B1[nn][kc], acc[r][nn], 0, 0, 0);
            }
        }
    }
    __syncthreads();

    // ---- bias + relu, write h (hi/lo) ----
    #pragma unroll
    for (int r = 0; r < 4; r++) {
        #pragma unroll
        for (int nn = 0; nn < 2; nn++) {
            const float bv = nn ? b1v1 : b1v0;
            const int col = wv * 32 + nn * 16 + la;
            #pragma unroll
            for (int i = 0; i < 4; i++) {
                float h = fmaxf(acc[r][nn][i] + bv, 0.f);
                int row = r * 16 + lb * 4 + i;
                _Float16 hh = (_Float16)h;
                xh[row][col] = hh;
                xl[row][col] = (_Float16)(h - (float)hh);
            }
        }
    }
    __syncthreads();

    // ---- layer 2 ----
    f4v acc2[4];
    #pragma unroll
    for (int r = 0; r < 4; r++) { f4v z = {0.f, 0.f, 0.f, 0.f}; acc2[r] = z; }
    #pragma unroll
    for (int r = 0; r < 4; r++) {
        h8 Ah[4], Al[4];
        #pragma unroll
        for (int kc = 0; kc < 4; kc++) {
            Ah[kc] = *(const h8*)&xh[r * 16 + la][kc * 32 + lb * 8];
            Al[kc] = *(const h8*)&xl[r * 16 + la][kc * 32 + lb * 8];
        }
        #pragma unroll
        for (int kc = 0; kc < 4; kc++) {
            acc2[r] = __builtin_amdgcn_mfma_f32_16x16x32_f16(Ah[kc], B2[kc], acc2[r], 0, 0, 0);
            acc2[r] = __builtin_amdgcn_mfma_f32_16x16x32_f16(Al[kc], B2[kc], acc2[r], 0, 0, 0);
        }
    }

    // ---- store fp32 canonical + fp16 mirror ----
    {
        const int col = wv * 16 + la;
        #pragma unroll
        for (int r = 0; r < 4; r++) {
            #pragma unroll
            for (int i = 0; i < 4; i++) {
                int row = r * 16 + lb * 4 + i;
                if (row < rem) {
                    float y = acc2[r][i] + b2v;
                    size_t idx = (size_t)(base + row) * 64 + col;
                    feat[idx] = y;
                    mirror[idx] = __float2half_rn(y);
                }
            }
        }
    }
}

// ---------------- output MLP via MFMA: 64 -> 128 relu -> 16, sigmoid ----------------
__global__ __launch_bounds__(256) void k_out3(const float* __restrict__ vars, float* __restrict__ out, int V,
                                              const float* __restrict__ w1, const float* __restrict__ b1,
                                              const float* __restrict__ w2, const float* __restrict__ b2) {
    __shared__ _Float16 xh[64][136];
    __shared__ _Float16 xl[64][136];
    const int t = threadIdx.x;
    const int base = blockIdx.x * 64;
    const int rem = V - base;
    const int wv = t >> 6;
    const int la = t & 15;
    const int lb = (t & 63) >> 4;

    // ---- stage x[64][64] hi/lo ----
    {
        const float4* v4p = (const float4*)(vars + (size_t)base * 64);
        #pragma unroll
        for (int j = 0; j < 4; j++) {
            int idx = j * 256 + t;
            int row = idx >> 4;
            int q   = idx & 15;
            float4 v = make_float4(0.f, 0.f, 0.f, 0.f);
            if (row < rem) v = v4p[row * 16 + q];
            int k = q * 4;
            h4 hi, lo;
            hi[0] = (_Float16)v.x; lo[0] = (_Float16)(v.x - (float)hi[0]);
            hi[1] = (_Float16)v.y; lo[1] = (_Float16)(v.y - (float)hi[1]);
            hi[2] = (_Float16)v.z; lo[2] = (_Float16)(v.z - (float)hi[2]);
            hi[3] = (_Float16)v.w; lo[3] = (_Float16)(v.w - (float)hi[3]);
            *(h4*)&xh[row][k] = hi;
            *(h4*)&xl[row][k] = lo;
        }
    }

    h8 B1[2][2];
    h8 B2[4];
    #pragma unroll
    for (int nn = 0; nn < 2; nn++) {
        int col = wv * 32 + nn * 16 + la;
        #pragma unroll
        for (int kc = 0; kc < 2; kc++) {
            int kb = kc * 32 + lb * 8;
            h8 bb;
            #pragma unroll
            for (int j = 0; j < 8; j++) bb[j] = (_Float16)w1[(kb + j) * 128 + col];
            B1[nn][kc] = bb;
        }
    }
    {
        int col = la;   // N=16
        #pragma unroll
        for (int kc = 0; kc < 4; kc++) {
            int kb = kc * 32 + lb * 8;
            h8 bb;
            #pragma unroll
            for (int j = 0; j < 8; j++) bb[j] = (_Float16)w2[(kb + j) * 16 + col];
            B2[kc] = bb;
        }
    }
    const float b1v0 = b1[wv * 32 + la];
    const float b1v1 = b1[wv * 32 + 16 + la];
    const float b2v  = b2[la];

    __syncthreads();

    // ---- layer 1: K=64 ----
    f4v acc[4][2];
    #pragma unroll
    for (int r = 0; r < 4; r++) {
        f4v z = {0.f, 0.f, 0.f, 0.f};
        acc[r][0] = z; acc[r][1] = z;
    }
    #pragma unroll
    for (int r = 0; r < 4; r++) {
        h8 Ah[2], Al[2];
        #pragma unroll
        for (int kc = 0; kc < 2; kc++) {
            Ah[kc] = *(const h8*)&xh[r * 16 + la][kc * 32 + lb * 8];
            Al[kc] = *(const h8*)&xl[r * 16 + la][kc * 32 + lb * 8];
        }
        #pragma unroll
        for (int nn = 0; nn < 2; nn++) {
            #pragma unroll
            for (int kc = 0; kc < 2; kc++) {
                acc[r][nn] = __builtin_amdgcn_mfma_f32_16x16x32_f16(Ah[kc], B1[nn][kc], acc[r][nn], 0, 0, 0);
                acc[r][nn] = __builtin_amdgcn_mfma_f32_16x16x32_f16(Al[kc], B1[nn][kc], acc[r][nn], 0, 0, 0);
            }
        }
    }
    __syncthreads();

    // ---- bias + relu -> h hi/lo ----
    #pragma unroll
    for (int r = 0; r < 4; r++) {
        #pragma unroll
        for (int nn = 0; nn < 2; nn++) {
            const float bv = nn ? b1v1 : b1v0;
            const int col = wv * 32 + nn * 16 + la;
            #pragma unroll
            for (int i = 0; i < 4; i++) {
                float h = fmaxf(acc[r][nn][i] + bv, 0.f);
                int row = r * 16 + lb * 4 + i;
                _Float16 hh = (_Float16)h;
                xh[row][col] = hh;
                xl[row][col] = (_Float16)(h - (float)hh);
            }
        }
    }
    __syncthreads();

    // ---- layer 2: y[64][16]; wave wv owns row-tile wv ----
    f4v acc2 = {0.f, 0.f, 0.f, 0.f};
    {
        h8 Ah[4], Al[4];
        #pragma unroll
        for (int kc = 0; kc < 4; kc++) {
            Ah[kc] = *(const h8*)&xh[wv * 16 + la][kc * 32 + lb * 8];
            Al[kc] = *(const h8*)&xl[wv * 16 + la][kc * 32 + lb * 8];
        }
        #pragma unroll
        for (int kc = 0; kc < 4; kc++) {
            acc2 = __builtin_amdgcn_mfma_f32_16x16x32_f16(Ah[kc], B2[kc], acc2, 0, 0, 0);
            acc2 = __builtin_amdgcn_mfma_f32_16x16x32_f16(Al[kc], B2[kc], acc2, 0, 0, 0);
        }
    }

    #pragma unroll
    for (int i = 0; i < 4; i++) {
        int row = wv * 16 + lb * 4 + i;
        if (row < rem) {
            float y = acc2[i] + b2v;
            out[(size_t)(base + row) * 16 + la] = 1.f / (1.f + __expf(-y));
        }
    }
}

// ---------------- launch ----------------

extern "C" void kernel_launch(void* const* d_in, const int* in_sizes, int n_in,
                              void* d_out, int out_size, void* d_ws, size_t ws_size,
                              hipStream_t stream) {
    const int*   row_idx = (const int*)d_in[0];
    const int*   col_idx = (const int*)d_in[1];
    const float* adj     = (const float*)d_in[2];
    const float* cond    = (const float*)d_in[3];
    const float* pc_w1  = (const float*)d_in[6];
    const float* pc_b1  = (const float*)d_in[7];
    const float* pc_w2  = (const float*)d_in[8];
    const float* pc_b2  = (const float*)d_in[9];
    const float* cu_w1  = (const float*)d_in[10];
    const float* cu_b1  = (const float*)d_in[11];
    const float* cu_w2  = (const float*)d_in[12];
    const float* cu_b2  = (const float*)d_in[13];
    const float* vu_w1  = (const float*)d_in[14];
    const float* vu_b1  = (const float*)d_in[15];
    const float* vu_w2  = (const float*)d_in[16];
    const float* vu_b2  = (const float*)d_in[17];
    const float* out_w1 = (const float*)d_in[18];
    const float* out_b1 = (const float*)d_in[19];
    const float* out_w2 = (const float*)d_in[20];
    const float* out_b2 = (const float*)d_in[21];

    const int NNZ = in_sizes[0];
    const int C   = in_sizes[3];
    const int V   = out_size / 16;

    const int NBc = (C + GB_D - 1) / GB_D;
    const int NBv = (V + GB_D - 1) / GB_D;
    const int NBT = NBc + NBv;

    float* out = (float*)d_out;

    // ---- workspace carve ----
    char* wsb = (char*)d_ws;
    size_t off = 0;
    auto carve = [&](size_t bytes) -> void* {
        void* p = wsb + off;
        off = (off + bytes + 255) & ~(size_t)255;
        return p;
    };
    float*  variables   = (float*)carve((size_t)V * 64 * 4);
    float*  constraints = (float*)carve((size_t)C * 64 * 4);
    float*  v2c         = (float*)carve((size_t)C * 64 * 4);
    float*  c2v         = (float*)carve((size_t)V * 64 * 4);
    __half* var_h       = (__half*)carve((size_t)V * 64 * 2);
    __half* con_h       = (__half*)carve((size_t)C * 64 * 2);
    int2*   pack        = (int2*)carve((size_t)2 * NNZ * 8);
    int*    bcnt        = (int*)carve((size_t)NBT * 4);
    int*    bptr        = (int*)carve((size_t)(NBT + 1) * 4);
    int*    bnxt        = (int*)carve((size_t)NBT * 4);
    int*    dptr_c      = (int*)carve((size_t)(C + 1) * 4);
    int*    dptr_v      = (int*)carve((size_t)(V + 1) * 4);
    float*  sumw        = (float*)carve((size_t)C * 4);
    (void)ws_size; (void)n_in;

    const size_t shmem = (size_t)NBT * 4;

    // ---- bucket-grouped, destination-sorted edge build ----
    hipMemsetAsync(bcnt, 0, (size_t)NBT * 4, stream);
    k_bhist<<<512, 256, shmem, stream>>>(row_idx, col_idx, NNZ, bcnt, NBc, NBT);
    k_bscan<<<1, 1024, 0, stream>>>(bcnt, NBT, bptr, bnxt);
    k_mpsplit<<<(NNZ + MS_CH - 1) / MS_CH, 256, shmem, stream>>>(row_idx, col_idx, adj, NNZ,
                                                                 bnxt, pack, NBc, NBT);
    k_bsort<<<NBT, 256, 0, stream>>>(bptr, pack, dptr_c, C, dptr_v, V, NBc, sumw);

    // ---- init features ----
    k_ones<<<2048, 256, 0, stream>>>((float4*)variables, V * 16);
    k_pc2<<<(C + 63) / 64, 256, 0, stream>>>(cond, constraints, con_h, C, pc_w1, pc_b1, pc_w2, pc_b2);

    // ---- message-passing rounds ----
    for (int p = 0; p < 3; p++) {
        if (p == 0) {
            // variables == 1  =>  v2c row = sumw broadcast (no gather needed)
            k_bcast<<<2048, 256, 0, stream>>>(sumw, (float4*)v2c, C * 16);
        } else {
            k_gather<<<2048, 256, 0, stream>>>(dptr_c, pack, var_h, v2c, C);
        }
        k_mlp3<<<(C + 63) / 64, 256, 0, stream>>>(constraints, v2c, con_h, C, cu_w1, cu_b1, cu_w2, cu_b2);
        k_gather<<<2048, 256, 0, stream>>>(dptr_v, pack, con_h, c2v, V);
        k_mlp3<<<(V + 63) / 64, 256, 0, stream>>>(variables, c2v, var_h, V, vu_w1, vu_b1, vu_w2, vu_b2);
    }

    // ---- output ----
    k_out3<<<(V + 63) / 64, 256, 0, stream>>>(variables, out, V, out_w1, out_b1, out_w2, out_b2);
}